// Round 1
// baseline (289.837 us; speedup 1.0000x reference)
//
#include <hip/hip_runtime.h>
#include <hip/hip_bf16.h>
#include <stdint.h>

typedef __bf16 bf16_t;
typedef bf16_t bf16x8 __attribute__((ext_vector_type(8)));
typedef float  f32x4  __attribute__((ext_vector_type(4)));
typedef float  f32x4v __attribute__((ext_vector_type(4)));

#define GAS __attribute__((address_space(1)))
#define LAS __attribute__((address_space(3)))

__device__ inline void gld_lds16(const void* g, void* l) {
    __builtin_amdgcn_global_load_lds((const GAS void*)g, (LAS void*)l, 16, 0, 0);
}

// ---------------- fp32 -> bf16 convert (n % 8 == 0) ----------------
__global__ __launch_bounds__(256) void k_cvt(const float* __restrict__ in,
                                             bf16_t* __restrict__ out, int n) {
    int i = (blockIdx.x * 256 + threadIdx.x) * 8;
    if (i >= n) return;
    f32x4v v0 = *(const f32x4v*)(in + i);
    f32x4v v1 = *(const f32x4v*)(in + i + 4);
    bf16x8 o;
    o[0] = (bf16_t)v0[0]; o[1] = (bf16_t)v0[1]; o[2] = (bf16_t)v0[2]; o[3] = (bf16_t)v0[3];
    o[4] = (bf16_t)v1[0]; o[5] = (bf16_t)v1[1]; o[6] = (bf16_t)v1[2]; o[7] = (bf16_t)v1[3];
    *(bf16x8*)(out + i) = o;
}

// ---------------- RoPE on bf16 [4096][1024], pairs along head-dim ----------------
__global__ __launch_bounds__(256) void k_rope(bf16_t* __restrict__ Q, bf16_t* __restrict__ Kt,
                                              const float* __restrict__ sn,
                                              const float* __restrict__ cs) {
    int idx = blockIdx.x * 256 + threadIdx.x;   // pair index, total 4096*512
    bf16_t* T = blockIdx.y ? Kt : Q;
    int row = idx >> 9;          // 0..4095
    int pi  = idx & 511;
    int h = pi >> 5, i = pi & 31;
    int p = row & 2047;
    float c = cs[p * 32 + i], s = sn[p * 32 + i];
    bf16_t* ptr = T + (size_t)row * 1024 + h * 64 + 2 * i;
    float e = (float)ptr[0], o = (float)ptr[1];
    ptr[0] = (bf16_t)(e * c - o * s);
    ptr[1] = (bf16_t)(e * s + o * c);
}

// ---------------- GEMM  C[M][N] = A[M][K] * B[N][K]^T  (bf16 in, OutT out) ----------------
// 128x128 tile, BK=32, 4 waves (2x2), m97-style global_load_lds staging.
template <typename OutT>
__global__ __launch_bounds__(256) void k_gemm_bt(
    const bf16_t* __restrict__ A,
    const bf16_t* __restrict__ B0, const bf16_t* __restrict__ B1, const bf16_t* __restrict__ B2,
    OutT* __restrict__ C0, OutT* __restrict__ C1, OutT* __restrict__ C2,
    int M, int N, int K) {
    const bf16_t* B = blockIdx.z == 0 ? B0 : (blockIdx.z == 1 ? B1 : B2);
    OutT*         C = blockIdx.z == 0 ? C0 : (blockIdx.z == 1 ? C1 : C2);
    const int BM = 128, BN = 128, BK = 32;
    __shared__ bf16_t As[BM * BK];
    __shared__ bf16_t Bs[BN * BK];
    int tid = threadIdx.x;
    int lane = tid & 63, wid = tid >> 6;
    int row0 = blockIdx.y * BM, col0 = blockIdx.x * BN;
    int wr = (wid >> 1) * 64, wc = (wid & 1) * 64;
    int lr = lane & 15, kg = lane >> 4;

    f32x4 acc[4][4];
#pragma unroll
    for (int i = 0; i < 4; ++i)
#pragma unroll
        for (int j = 0; j < 4; ++j) acc[i][j] = (f32x4){0.f, 0.f, 0.f, 0.f};

    int ob = tid * 16;  // byte offset within a 4096-byte staging pass
    for (int k0 = 0; k0 < K; k0 += BK) {
        __syncthreads();
#pragma unroll
        for (int p = 0; p < 2; ++p) {
            int off = p * 4096 + ob;
            int r = off >> 6;      // 64 bytes per 32-elem row
            int cb = off & 63;
            gld_lds16((const char*)A + ((size_t)(row0 + r) * K + k0) * 2 + cb, (char*)As + off);
            gld_lds16((const char*)B + ((size_t)(col0 + r) * K + k0) * 2 + cb, (char*)Bs + off);
        }
        __syncthreads();
        bf16x8 af[4], bfr[4];
#pragma unroll
        for (int mi = 0; mi < 4; ++mi)
            af[mi] = *(const bf16x8*)&As[(wr + mi * 16 + lr) * BK + kg * 8];
#pragma unroll
        for (int ni = 0; ni < 4; ++ni)
            bfr[ni] = *(const bf16x8*)&Bs[(wc + ni * 16 + lr) * BK + kg * 8];
#pragma unroll
        for (int mi = 0; mi < 4; ++mi)
#pragma unroll
            for (int ni = 0; ni < 4; ++ni)
                acc[mi][ni] = __builtin_amdgcn_mfma_f32_16x16x32_bf16(af[mi], bfr[ni],
                                                                      acc[mi][ni], 0, 0, 0);
    }
#pragma unroll
    for (int mi = 0; mi < 4; ++mi)
#pragma unroll
        for (int ni = 0; ni < 4; ++ni)
#pragma unroll
            for (int r = 0; r < 4; ++r) {
                int row = row0 + wr + mi * 16 + kg * 4 + r;
                int col = col0 + wc + ni * 16 + lr;
                C[(size_t)row * N + col] = (OutT)acc[mi][ni][r];
            }
}

// ---------------- Flash attention, causal, no scale (matches reference) ----------------
// grid (32 qblocks, 16 heads, 2 batch); 4 waves; each wave owns 16 q-rows.
__global__ __launch_bounds__(256) void k_flash(const bf16_t* __restrict__ Q,
                                               const bf16_t* __restrict__ Kt,
                                               const bf16_t* __restrict__ V,
                                               bf16_t* __restrict__ Ob) {
    const int DM = 1024, S = 2048;
    int qb = blockIdx.x, h = blockIdx.y, b = blockIdx.z;
    int tid = threadIdx.x, lane = tid & 63, wid = tid >> 6;
    int lr = lane & 15, kg = lane >> 4;
    int rowbase = b * S;
    int colbase = h * 64;
    __shared__ bf16_t Ks[64 * 64];
    __shared__ bf16_t Vts[64 * 64];
    __shared__ bf16_t Ps[4][16 * 64];

    int qrow0 = qb * 64 + wid * 16;
    bf16x8 qf[2];
#pragma unroll
    for (int s = 0; s < 2; ++s)
        qf[s] = *(const bf16x8*)&Q[(size_t)(rowbase + qrow0 + lr) * DM + colbase + s * 32 + kg * 8];

    f32x4 Oa[4];
    float m_run[4], l_run[4];
#pragma unroll
    for (int i = 0; i < 4; ++i) {
        Oa[i] = (f32x4){0.f, 0.f, 0.f, 0.f};
        m_run[i] = -1e30f;
        l_run[i] = 0.f;
    }

    for (int kb = 0; kb <= qb; ++kb) {
        __syncthreads();
#pragma unroll
        for (int p = 0; p < 2; ++p) {
            int e = p * 2048 + tid * 8;
            int r = e >> 6, c = e & 63;
            size_t gro = (size_t)(rowbase + kb * 64 + r) * DM + colbase + c;
            bf16x8 kv = *(const bf16x8*)&Kt[gro];
            *(bf16x8*)&Ks[r * 64 + c] = kv;
            bf16x8 vv = *(const bf16x8*)&V[gro];
#pragma unroll
            for (int j = 0; j < 8; ++j) Vts[(c + j) * 64 + r] = vv[j];
        }
        __syncthreads();

        f32x4 sa[4];
#pragma unroll
        for (int ni = 0; ni < 4; ++ni) sa[ni] = (f32x4){0.f, 0.f, 0.f, 0.f};
#pragma unroll
        for (int s = 0; s < 2; ++s)
#pragma unroll
            for (int ni = 0; ni < 4; ++ni) {
                bf16x8 kf = *(const bf16x8*)&Ks[(ni * 16 + lr) * 64 + s * 32 + kg * 8];
                sa[ni] = __builtin_amdgcn_mfma_f32_16x16x32_bf16(qf[s], kf, sa[ni], 0, 0, 0);
            }

#pragma unroll
        for (int r = 0; r < 4; ++r) {
            int qpos = qrow0 + kg * 4 + r;
            float mx = -1e30f;
#pragma unroll
            for (int ni = 0; ni < 4; ++ni) {
                int ck = kb * 64 + ni * 16 + lr;
                float v = sa[ni][r];
                if (ck > qpos) { v = -1e30f; sa[ni][r] = v; }
                mx = fmaxf(mx, v);
            }
#pragma unroll
            for (int off = 1; off < 16; off <<= 1) mx = fmaxf(mx, __shfl_xor(mx, off));
            float mo = m_run[r];
            float mn = fmaxf(mo, mx);
            float scale = __expf(mo - mn);
            float rs = 0.f;
#pragma unroll
            for (int ni = 0; ni < 4; ++ni) {
                float pv = __expf(sa[ni][r] - mn);
                sa[ni][r] = pv;
                rs += pv;
            }
#pragma unroll
            for (int off = 1; off < 16; off <<= 1) rs += __shfl_xor(rs, off);
            l_run[r] = l_run[r] * scale + rs;
            m_run[r] = mn;
#pragma unroll
            for (int ni = 0; ni < 4; ++ni) Oa[ni][r] *= scale;
        }

#pragma unroll
        for (int r = 0; r < 4; ++r)
#pragma unroll
            for (int ni = 0; ni < 4; ++ni)
                Ps[wid][(kg * 4 + r) * 64 + ni * 16 + lr] = (bf16_t)sa[ni][r];
        __syncthreads();

#pragma unroll
        for (int s = 0; s < 2; ++s) {
            bf16x8 pf = *(const bf16x8*)&Ps[wid][lr * 64 + s * 32 + kg * 8];
#pragma unroll
            for (int ni = 0; ni < 4; ++ni) {
                bf16x8 vf = *(const bf16x8*)&Vts[(ni * 16 + lr) * 64 + s * 32 + kg * 8];
                Oa[ni] = __builtin_amdgcn_mfma_f32_16x16x32_bf16(pf, vf, Oa[ni], 0, 0, 0);
            }
        }
    }

#pragma unroll
    for (int r = 0; r < 4; ++r) {
        int row = rowbase + qrow0 + kg * 4 + r;
        float inv = 1.f / l_run[r];
#pragma unroll
        for (int ni = 0; ni < 4; ++ni)
            Ob[(size_t)row * DM + colbase + ni * 16 + lr] = (bf16_t)(Oa[ni][r] * inv);
    }
}

extern "C" void kernel_launch(void* const* d_in, const int* in_sizes, int n_in,
                              void* d_out, int out_size, void* d_ws, size_t ws_size,
                              hipStream_t stream) {
    const float* x  = (const float*)d_in[0];
    const float* wk = (const float*)d_in[1];  // key_weight
    const float* wq = (const float*)d_in[2];  // query_weight
    const float* wv = (const float*)d_in[3];  // value_weight
    const float* wo = (const float*)d_in[4];  // output_weight
    const float* sn = (const float*)d_in[5];
    const float* cs = (const float*)d_in[6];
    float* out = (float*)d_out;
    (void)in_sizes; (void)n_in; (void)out_size; (void)ws_size;

    char* ws = (char*)d_ws;
    const size_t MB = 1024 * 1024;
    bf16_t* xb  = (bf16_t*)(ws + 0);        // 4096x1024
    bf16_t* wqb = (bf16_t*)(ws + 8 * MB);   // 1024x1024
    bf16_t* wkb = (bf16_t*)(ws + 10 * MB);
    bf16_t* wvb = (bf16_t*)(ws + 12 * MB);
    bf16_t* wob = (bf16_t*)(ws + 14 * MB);
    bf16_t* Qb  = (bf16_t*)(ws + 16 * MB);  // 4096x1024 each
    bf16_t* Kb  = (bf16_t*)(ws + 24 * MB);
    bf16_t* Vb  = (bf16_t*)(ws + 32 * MB);
    bf16_t* Ob  = (bf16_t*)(ws + 40 * MB);

    k_cvt<<<2048, 256, 0, stream>>>(x, xb, 4194304);
    k_cvt<<<512, 256, 0, stream>>>(wq, wqb, 1048576);
    k_cvt<<<512, 256, 0, stream>>>(wk, wkb, 1048576);
    k_cvt<<<512, 256, 0, stream>>>(wv, wvb, 1048576);
    k_cvt<<<512, 256, 0, stream>>>(wo, wob, 1048576);

    // Q/K/V projections: C[bp][h*64+d] = sum_m x[bp][m] * W[h*64+d][m]
    k_gemm_bt<bf16_t><<<dim3(8, 32, 3), 256, 0, stream>>>(
        xb, wqb, wkb, wvb, Qb, Kb, Vb, 4096, 1024, 1024);

    k_rope<<<dim3(8192, 2), 256, 0, stream>>>(Qb, Kb, sn, cs);

    k_flash<<<dim3(32, 16, 2), 256, 0, stream>>>(Qb, Kb, Vb, Ob);

    // out[bp][m] = sum_hd Ob[bp][hd] * wo[m][hd]
    k_gemm_bt<float><<<dim3(8, 32, 1), 256, 0, stream>>>(
        Ob, wob, wob, wob, out, out, out, 4096, 1024, 1024);
}

// Round 4
// 192.957 us; speedup vs baseline: 1.5021x; 1.5021x over previous
//
#include <hip/hip_runtime.h>
#include <hip/hip_bf16.h>
#include <stdint.h>

typedef __bf16 bf16_t;
typedef bf16_t bf16x8 __attribute__((ext_vector_type(8)));
typedef float  f32x4  __attribute__((ext_vector_type(4)));

#define GAS __attribute__((address_space(1)))
#define LAS __attribute__((address_space(3)))

__device__ inline void gld_lds16(const void* g, void* l) {
    __builtin_amdgcn_global_load_lds((const GAS void*)g, (LAS void*)l, 16, 0, 0);
}

// byte offset into a [rows][64] bf16 tile (128B rows), XOR-swizzled (T2)
__device__ inline int swz(int row, int colbyte) {
    return row * 128 + (colbyte ^ ((row & 7) << 4));
}

// ---------------- fp32 -> bf16 convert, all 5 tensors in one launch ----------------
__global__ __launch_bounds__(256) void k_cvt5(const float* __restrict__ i0, bf16_t* __restrict__ o0,
                                              const float* __restrict__ i1, bf16_t* __restrict__ o1,
                                              const float* __restrict__ i2, bf16_t* __restrict__ o2,
                                              const float* __restrict__ i3, bf16_t* __restrict__ o3,
                                              const float* __restrict__ i4, bf16_t* __restrict__ o4) {
    const float* in; bf16_t* out; int n;
    switch (blockIdx.y) {
        case 0: in = i0; out = o0; n = 4194304; break;
        case 1: in = i1; out = o1; n = 1048576; break;
        case 2: in = i2; out = o2; n = 1048576; break;
        case 3: in = i3; out = o3; n = 1048576; break;
        default: in = i4; out = o4; n = 1048576; break;
    }
    int i = (blockIdx.x * 256 + threadIdx.x) * 8;
    if (i >= n) return;
    f32x4 v0 = *(const f32x4*)(in + i);
    f32x4 v1 = *(const f32x4*)(in + i + 4);
    bf16x8 o;
    o[0] = (bf16_t)v0[0]; o[1] = (bf16_t)v0[1]; o[2] = (bf16_t)v0[2]; o[3] = (bf16_t)v0[3];
    o[4] = (bf16_t)v1[0]; o[5] = (bf16_t)v1[1]; o[6] = (bf16_t)v1[2]; o[7] = (bf16_t)v1[3];
    *(bf16x8*)(out + i) = o;
}

// ---------------- RoPE on bf16 [4096][1024], pairs along head-dim ----------------
__global__ __launch_bounds__(256) void k_rope(bf16_t* __restrict__ Q, bf16_t* __restrict__ Kt,
                                              const float* __restrict__ sn,
                                              const float* __restrict__ cs) {
    int idx = blockIdx.x * 256 + threadIdx.x;   // pair index, total 4096*512
    bf16_t* T = blockIdx.y ? Kt : Q;
    int row = idx >> 9;          // 0..4095
    int pi  = idx & 511;
    int h = pi >> 5, i = pi & 31;
    int p = row & 2047;
    float c = cs[p * 32 + i], s = sn[p * 32 + i];
    bf16_t* ptr = T + (size_t)row * 1024 + h * 64 + 2 * i;
    float e = (float)ptr[0], o = (float)ptr[1];
    ptr[0] = (bf16_t)(e * c - o * s);
    ptr[1] = (bf16_t)(e * s + o * c);
}

// ---------------- GEMM  C[M][N] = A[M][K] * B[N][K]^T  (bf16 in, OutT out) ----------------
template <typename OutT>
__global__ __launch_bounds__(256) void k_gemm_bt(
    const bf16_t* __restrict__ A,
    const bf16_t* __restrict__ B0, const bf16_t* __restrict__ B1,
    OutT* __restrict__ C0, OutT* __restrict__ C1,
    int M, int N, int K) {
    const bf16_t* B = blockIdx.z == 0 ? B0 : B1;
    OutT*         C = blockIdx.z == 0 ? C0 : C1;
    const int BK = 32;
    __shared__ bf16_t As[128 * BK];
    __shared__ bf16_t Bs[128 * BK];
    int tid = threadIdx.x;
    int lane = tid & 63, wid = tid >> 6;
    int row0 = blockIdx.y * 128, col0 = blockIdx.x * 128;
    int wr = (wid >> 1) * 64, wc = (wid & 1) * 64;
    int lr = lane & 15, kg = lane >> 4;

    f32x4 acc[4][4];
#pragma unroll
    for (int i = 0; i < 4; ++i)
#pragma unroll
        for (int j = 0; j < 4; ++j) acc[i][j] = (f32x4){0.f, 0.f, 0.f, 0.f};

    int ob = tid * 16;  // byte offset within a 4096-byte staging pass
    for (int k0 = 0; k0 < K; k0 += BK) {
        __syncthreads();
#pragma unroll
        for (int p = 0; p < 2; ++p) {
            int off = p * 4096 + ob;
            int r = off >> 6;      // 64 bytes per 32-elem row
            int cb = off & 63;
            gld_lds16((const char*)A + ((size_t)(row0 + r) * K + k0) * 2 + cb, (char*)As + off);
            gld_lds16((const char*)B + ((size_t)(col0 + r) * K + k0) * 2 + cb, (char*)Bs + off);
        }
        __syncthreads();
        bf16x8 af[4], bfr[4];
#pragma unroll
        for (int mi = 0; mi < 4; ++mi)
            af[mi] = *(const bf16x8*)&As[(wr + mi * 16 + lr) * BK + kg * 8];
#pragma unroll
        for (int ni = 0; ni < 4; ++ni)
            bfr[ni] = *(const bf16x8*)&Bs[(wc + ni * 16 + lr) * BK + kg * 8];
#pragma unroll
        for (int mi = 0; mi < 4; ++mi)
#pragma unroll
            for (int ni = 0; ni < 4; ++ni)
                acc[mi][ni] = __builtin_amdgcn_mfma_f32_16x16x32_bf16(af[mi], bfr[ni],
                                                                      acc[mi][ni], 0, 0, 0);
    }
#pragma unroll
    for (int mi = 0; mi < 4; ++mi)
#pragma unroll
        for (int ni = 0; ni < 4; ++ni)
#pragma unroll
            for (int r = 0; r < 4; ++r) {
                int row = row0 + wr + mi * 16 + kg * 4 + r;
                int col = col0 + wc + ni * 16 + lr;
                C[(size_t)row * N + col] = (OutT)acc[mi][ni][r];
            }
}

// ---------------- Flash attention, causal ----------------
// grid (32, 16, 2); 4 waves; wave owns 16 q-rows. K row-major, V pre-transposed.
// Double-buffered reg-staged K/V tiles, XOR-swizzled LDS, 1 barrier/iter.
__global__ __launch_bounds__(256) void k_flash(const bf16_t* __restrict__ Q,
                                               const bf16_t* __restrict__ Kt,
                                               const bf16_t* __restrict__ Vt,
                                               bf16_t* __restrict__ Ob) {
    const int DM = 1024, S = 2048;
    // per-CU load balancing: heads 8..15 walk q-tiles in reverse
    int qb = (blockIdx.y & 8) ? (31 - blockIdx.x) : blockIdx.x;
    int h = blockIdx.y, b = blockIdx.z;
    int tid = threadIdx.x, lane = tid & 63, wid = tid >> 6;
    int lr = lane & 15, kg = lane >> 4;
    int rowbase = b * S;
    int colbase = h * 64;

    __shared__ bf16_t Ks[2][64 * 64];
    __shared__ bf16_t Vs[2][64 * 64];   // [d][k] per tile
    __shared__ bf16_t Ps[4][16 * 64];

    int qrow0 = qb * 64 + wid * 16;
    bf16x8 qf[2];
#pragma unroll
    for (int s = 0; s < 2; ++s)
        qf[s] = *(const bf16x8*)&Q[(size_t)(rowbase + qrow0 + lr) * DM + colbase + s * 32 + kg * 8];

    f32x4 Oa[4];
    float m_run[4], l_run[4];
#pragma unroll
    for (int i = 0; i < 4; ++i) {
        Oa[i] = (f32x4){0.f, 0.f, 0.f, 0.f};
        m_run[i] = -1e30f;
        l_run[i] = 0.f;
    }

    // staging geometry: 256 threads x 2 passes x bf16x8 covers a 64x64 tile
    int r0 = tid >> 3;            // 0..31, +32 on pass 1
    int c0 = (tid & 7) * 8;       // element col
    const bf16_t* Kg = Kt + (size_t)rowbase * DM + colbase;
    const bf16_t* Vg = Vt + (size_t)colbase * 4096 + b * S;

    bf16x8 kr[2], vr[2];
#define LOADKV(kb, kr_, vr_)                                                      \
    _Pragma("unroll") for (int p = 0; p < 2; ++p) {                               \
        int r = p * 32 + r0;                                                      \
        kr_[p] = *(const bf16x8*)&Kg[(size_t)((kb) * 64 + r) * DM + c0];          \
        vr_[p] = *(const bf16x8*)&Vg[(size_t)r * 4096 + (kb) * 64 + c0];          \
    }
#define STOREKV(bi, kr_, vr_)                                                     \
    _Pragma("unroll") for (int p = 0; p < 2; ++p) {                               \
        int r = p * 32 + r0;                                                      \
        *(bf16x8*)((char*)&Ks[bi][0] + swz(r, c0 * 2)) = kr_[p];                  \
        *(bf16x8*)((char*)&Vs[bi][0] + swz(r, c0 * 2)) = vr_[p];                  \
    }

    LOADKV(0, kr, vr);
    STOREKV(0, kr, vr);
    __syncthreads();

    int cur = 0;
    for (int kb = 0; kb <= qb; ++kb) {
        bf16x8 kr2[2], vr2[2];
        if (kb < qb) { LOADKV(kb + 1, kr2, vr2); }

        // ---- QK^T ----
        f32x4 sa[4];
#pragma unroll
        for (int ni = 0; ni < 4; ++ni) sa[ni] = (f32x4){0.f, 0.f, 0.f, 0.f};
#pragma unroll
        for (int s = 0; s < 2; ++s)
#pragma unroll
            for (int ni = 0; ni < 4; ++ni) {
                bf16x8 kf = *(const bf16x8*)((char*)&Ks[cur][0] + swz(ni * 16 + lr, s * 64 + kg * 16));
                sa[ni] = __builtin_amdgcn_mfma_f32_16x16x32_bf16(qf[s], kf, sa[ni], 0, 0, 0);
            }

        // ---- online softmax (rows spread over 16 lanes) ----
#pragma unroll
        for (int r = 0; r < 4; ++r) {
            int qpos = qrow0 + kg * 4 + r;
            float mx = -1e30f;
#pragma unroll
            for (int ni = 0; ni < 4; ++ni) {
                int ck = kb * 64 + ni * 16 + lr;
                float v = sa[ni][r];
                if (ck > qpos) { v = -1e30f; sa[ni][r] = v; }
                mx = fmaxf(mx, v);
            }
#pragma unroll
            for (int off = 1; off < 16; off <<= 1) mx = fmaxf(mx, __shfl_xor(mx, off));
            float mo = m_run[r];
            float mn = fmaxf(mo, mx);
            float scale = __expf(mo - mn);
            float rs = 0.f;
#pragma unroll
            for (int ni = 0; ni < 4; ++ni) {
                float pv = __expf(sa[ni][r] - mn);
                sa[ni][r] = pv;
                rs += pv;
            }
#pragma unroll
            for (int off = 1; off < 16; off <<= 1) rs += __shfl_xor(rs, off);
            l_run[r] = l_run[r] * scale + rs;
            m_run[r] = mn;
#pragma unroll
            for (int ni = 0; ni < 4; ++ni) Oa[ni][r] *= scale;
        }

        // ---- P -> LDS (per-wave buffer, no block barrier needed) ----
#pragma unroll
        for (int r = 0; r < 4; ++r)
#pragma unroll
            for (int ni = 0; ni < 4; ++ni)
                *(bf16_t*)((char*)&Ps[wid][0] + swz(kg * 4 + r, (ni * 16 + lr) * 2)) =
                    (bf16_t)sa[ni][r];

        // ---- PV ----
#pragma unroll
        for (int s = 0; s < 2; ++s) {
            bf16x8 pf = *(const bf16x8*)((char*)&Ps[wid][0] + swz(lr, s * 64 + kg * 16));
#pragma unroll
            for (int ni = 0; ni < 4; ++ni) {
                bf16x8 vf = *(const bf16x8*)((char*)&Vs[cur][0] + swz(ni * 16 + lr, s * 64 + kg * 16));
                Oa[ni] = __builtin_amdgcn_mfma_f32_16x16x32_bf16(pf, vf, Oa[ni], 0, 0, 0);
            }
        }

        if (kb < qb) {
            STOREKV(cur ^ 1, kr2, vr2);
            __syncthreads();
            cur ^= 1;
        }
    }

#pragma unroll
    for (int r = 0; r < 4; ++r) {
        int row = rowbase + qrow0 + kg * 4 + r;
        float inv = 1.f / l_run[r];
#pragma unroll
        for (int ni = 0; ni < 4; ++ni)
            Ob[(size_t)row * DM + colbase + ni * 16 + lr] = (bf16_t)(Oa[ni][r] * inv);
    }
}

extern "C" void kernel_launch(void* const* d_in, const int* in_sizes, int n_in,
                              void* d_out, int out_size, void* d_ws, size_t ws_size,
                              hipStream_t stream) {
    const float* x  = (const float*)d_in[0];
    const float* wk = (const float*)d_in[1];  // key_weight
    const float* wq = (const float*)d_in[2];  // query_weight
    const float* wv = (const float*)d_in[3];  // value_weight
    const float* wo = (const float*)d_in[4];  // output_weight
    const float* sn = (const float*)d_in[5];
    const float* cs = (const float*)d_in[6];
    float* out = (float*)d_out;
    (void)in_sizes; (void)n_in; (void)out_size; (void)ws_size;

    char* ws = (char*)d_ws;
    const size_t MB = 1024 * 1024;
    bf16_t* xb  = (bf16_t*)(ws + 0);        // 4096x1024
    bf16_t* wqb = (bf16_t*)(ws + 8 * MB);   // 1024x1024
    bf16_t* wkb = (bf16_t*)(ws + 10 * MB);
    bf16_t* wvb = (bf16_t*)(ws + 12 * MB);
    bf16_t* wob = (bf16_t*)(ws + 14 * MB);
    bf16_t* Qb  = (bf16_t*)(ws + 16 * MB);  // 4096x1024
    bf16_t* Kb  = (bf16_t*)(ws + 24 * MB);  // 4096x1024
    bf16_t* Vtb = (bf16_t*)(ws + 32 * MB);  // 1024x4096 (V^T: [h*64+d][b*2048+s])
    bf16_t* Ob  = (bf16_t*)(ws + 40 * MB);  // 4096x1024

    k_cvt5<<<dim3(2048, 5), 256, 0, stream>>>(x, xb, wq, wqb, wk, wkb, wv, wvb, wo, wob);

    // Q/K projections: C[bp][h*64+d] = sum_m x[bp][m] * W[h*64+d][m]
    k_gemm_bt<bf16_t><<<dim3(8, 32, 2), 256, 0, stream>>>(
        xb, wqb, wkb, Qb, Kb, 4096, 1024, 1024);
    // V projection, output-transposed: Vt[h*64+d][b*2048+s] = sum_m Wv[hd][m] x[bs][m]
    k_gemm_bt<bf16_t><<<dim3(32, 8, 1), 256, 0, stream>>>(
        wvb, xb, xb, Vtb, Vtb, 1024, 4096, 1024);

    k_rope<<<dim3(8192, 2), 256, 0, stream>>>(Qb, Kb, sn, cs);

    k_flash<<<dim3(32, 16, 2), 256, 0, stream>>>(Qb, Kb, Vtb, Ob);

    // out[bp][m] = sum_hd Ob[bp][hd] * wo[m][hd]
    k_gemm_bt<float><<<dim3(8, 32, 1), 256, 0, stream>>>(
        Ob, wob, wob, out, out, 4096, 1024, 1024);
}

// Round 5
// 192.092 us; speedup vs baseline: 1.5088x; 1.0045x over previous
//
#include <hip/hip_runtime.h>
#include <hip/hip_bf16.h>
#include <stdint.h>

typedef __bf16 bf16_t;
typedef bf16_t bf16x8 __attribute__((ext_vector_type(8)));
typedef float  f32x4  __attribute__((ext_vector_type(4)));

#define GAS __attribute__((address_space(1)))
#define LAS __attribute__((address_space(3)))

__device__ inline void gld_lds16(const void* g, void* l) {
    __builtin_amdgcn_global_load_lds((const GAS void*)g, (LAS void*)l, 16, 0, 0);
}

// byte offset into a [rows][64] bf16 tile (128B rows), XOR-swizzled (T2)
__device__ inline int swz(int row, int colbyte) {
    return row * 128 + (colbyte ^ ((row & 7) << 4));
}

// ---------------- fp32 -> bf16 convert, all 5 tensors in one launch ----------------
__global__ __launch_bounds__(256) void k_cvt5(const float* __restrict__ i0, bf16_t* __restrict__ o0,
                                              const float* __restrict__ i1, bf16_t* __restrict__ o1,
                                              const float* __restrict__ i2, bf16_t* __restrict__ o2,
                                              const float* __restrict__ i3, bf16_t* __restrict__ o3,
                                              const float* __restrict__ i4, bf16_t* __restrict__ o4) {
    const float* in; bf16_t* out; int n;
    switch (blockIdx.y) {
        case 0: in = i0; out = o0; n = 4194304; break;
        case 1: in = i1; out = o1; n = 1048576; break;
        case 2: in = i2; out = o2; n = 1048576; break;
        case 3: in = i3; out = o3; n = 1048576; break;
        default: in = i4; out = o4; n = 1048576; break;
    }
    int i = (blockIdx.x * 256 + threadIdx.x) * 8;
    if (i >= n) return;
    f32x4 v0 = *(const f32x4*)(in + i);
    f32x4 v1 = *(const f32x4*)(in + i + 4);
    bf16x8 o;
    o[0] = (bf16_t)v0[0]; o[1] = (bf16_t)v0[1]; o[2] = (bf16_t)v0[2]; o[3] = (bf16_t)v0[3];
    o[4] = (bf16_t)v1[0]; o[5] = (bf16_t)v1[1]; o[6] = (bf16_t)v1[2]; o[7] = (bf16_t)v1[3];
    *(bf16x8*)(out + i) = o;
}

// ---------------- RoPE on bf16 [4096][1024], pairs along head-dim ----------------
__global__ __launch_bounds__(256) void k_rope(bf16_t* __restrict__ Q, bf16_t* __restrict__ Kt,
                                              const float* __restrict__ sn,
                                              const float* __restrict__ cs) {
    int idx = blockIdx.x * 256 + threadIdx.x;   // pair index, total 4096*512
    bf16_t* T = blockIdx.y ? Kt : Q;
    int row = idx >> 9;          // 0..4095
    int pi  = idx & 511;
    int h = pi >> 5, i = pi & 31;
    int p = row & 2047;
    float c = cs[p * 32 + i], s = sn[p * 32 + i];
    bf16_t* ptr = T + (size_t)row * 1024 + h * 64 + 2 * i;
    float e = (float)ptr[0], o = (float)ptr[1];
    ptr[0] = (bf16_t)(e * c - o * s);
    ptr[1] = (bf16_t)(e * s + o * c);
}

// ---------------- GEMM  C[M][N] = A[M][K] * B[N][K]^T  (bf16 in, OutT out) ----------------
template <typename OutT>
__global__ __launch_bounds__(256) void k_gemm_bt(
    const bf16_t* __restrict__ A,
    const bf16_t* __restrict__ B0, const bf16_t* __restrict__ B1,
    OutT* __restrict__ C0, OutT* __restrict__ C1,
    int M, int N, int K) {
    const bf16_t* B = blockIdx.z == 0 ? B0 : B1;
    OutT*         C = blockIdx.z == 0 ? C0 : C1;
    const int BK = 32;
    __shared__ bf16_t As[128 * BK];
    __shared__ bf16_t Bs[128 * BK];
    int tid = threadIdx.x;
    int lane = tid & 63, wid = tid >> 6;
    int row0 = blockIdx.y * 128, col0 = blockIdx.x * 128;
    int wr = (wid >> 1) * 64, wc = (wid & 1) * 64;
    int lr = lane & 15, kg = lane >> 4;

    f32x4 acc[4][4];
#pragma unroll
    for (int i = 0; i < 4; ++i)
#pragma unroll
        for (int j = 0; j < 4; ++j) acc[i][j] = (f32x4){0.f, 0.f, 0.f, 0.f};

    int ob = tid * 16;  // byte offset within a 4096-byte staging pass
    for (int k0 = 0; k0 < K; k0 += BK) {
        __syncthreads();
#pragma unroll
        for (int p = 0; p < 2; ++p) {
            int off = p * 4096 + ob;
            int r = off >> 6;      // 64 bytes per 32-elem row
            int cb = off & 63;
            gld_lds16((const char*)A + ((size_t)(row0 + r) * K + k0) * 2 + cb, (char*)As + off);
            gld_lds16((const char*)B + ((size_t)(col0 + r) * K + k0) * 2 + cb, (char*)Bs + off);
        }
        __syncthreads();
        bf16x8 af[4], bfr[4];
#pragma unroll
        for (int mi = 0; mi < 4; ++mi)
            af[mi] = *(const bf16x8*)&As[(wr + mi * 16 + lr) * BK + kg * 8];
#pragma unroll
        for (int ni = 0; ni < 4; ++ni)
            bfr[ni] = *(const bf16x8*)&Bs[(wc + ni * 16 + lr) * BK + kg * 8];
#pragma unroll
        for (int mi = 0; mi < 4; ++mi)
#pragma unroll
            for (int ni = 0; ni < 4; ++ni)
                acc[mi][ni] = __builtin_amdgcn_mfma_f32_16x16x32_bf16(af[mi], bfr[ni],
                                                                      acc[mi][ni], 0, 0, 0);
    }
#pragma unroll
    for (int mi = 0; mi < 4; ++mi)
#pragma unroll
        for (int ni = 0; ni < 4; ++ni)
#pragma unroll
            for (int r = 0; r < 4; ++r) {
                int row = row0 + wr + mi * 16 + kg * 4 + r;
                int col = col0 + wc + ni * 16 + lr;
                C[(size_t)row * N + col] = (OutT)acc[mi][ni][r];
            }
}

// ---------------- Flash attention, causal, wave-independent ----------------
// grid (8, 16, 2) x 256 threads. Each wave handles two 32-row q-strips
// (j and 63-j) sequentially => every wave does exactly 33 tile-iters.
// K and V^T MFMA fragments are read directly from global (L1/L2-hot);
// no block barriers anywhere. P goes through a private 4KB LDS region.
__global__ __launch_bounds__(256) void k_flash(const bf16_t* __restrict__ Q,
                                               const bf16_t* __restrict__ K,
                                               const bf16_t* __restrict__ Vt,
                                               bf16_t* __restrict__ Ob) {
    const int DM = 1024, S = 2048, NB = 4096;
    int h = blockIdx.y, b = blockIdx.z;
    int tid = threadIdx.x, lane = tid & 63, wid = tid >> 6;
    int lr = lane & 15, kg = lane >> 4;
    int rowbase = b * S;
    int colbase = h * 64;
    int j = blockIdx.x * 4 + wid;      // 0..31

    __shared__ bf16_t Ps[4][32 * 64];
    char* Pw = (char*)&Ps[wid][0];

    const bf16_t* Kg = K + (size_t)rowbase * DM + colbase;   // [k][d] tile base
    const bf16_t* Vg = Vt + (size_t)colbase * NB + rowbase;  // [d][k] tile base

#define LOADK(kb, dst)                                                               \
    _Pragma("unroll") for (int ni = 0; ni < 4; ++ni)                                 \
    _Pragma("unroll") for (int s2 = 0; s2 < 2; ++s2)                                 \
        dst[ni * 2 + s2] =                                                           \
            *(const bf16x8*)&Kg[(size_t)((kb) * 64 + ni * 16 + lr) * DM + s2 * 32 + kg * 8];

#define LOADV(kb, dst)                                                               \
    _Pragma("unroll") for (int ni = 0; ni < 4; ++ni)                                 \
    _Pragma("unroll") for (int s2 = 0; s2 < 2; ++s2)                                 \
        dst[ni * 2 + s2] =                                                           \
            *(const bf16x8*)&Vg[(size_t)(ni * 16 + lr) * NB + (kb) * 64 + s2 * 32 + kg * 8];

#define STEP(kb, kf, vf, kfN, vfN)                                                   \
    {                                                                                \
        f32x4 sa[2][4];                                                              \
        _Pragma("unroll") for (int mi = 0; mi < 2; ++mi)                             \
        _Pragma("unroll") for (int ni = 0; ni < 4; ++ni)                             \
            sa[mi][ni] = (f32x4){0.f, 0.f, 0.f, 0.f};                                \
        _Pragma("unroll") for (int s2 = 0; s2 < 2; ++s2)                             \
        _Pragma("unroll") for (int ni = 0; ni < 4; ++ni)                             \
        _Pragma("unroll") for (int mi = 0; mi < 2; ++mi)                             \
            sa[mi][ni] = __builtin_amdgcn_mfma_f32_16x16x32_bf16(                    \
                qf[mi][s2], kf[ni * 2 + s2], sa[mi][ni], 0, 0, 0);                   \
        if ((kb) < kbmax) { LOADK((kb) + 1, kfN); }                                  \
        if ((kb) == kbmax) { /* causal mask, diagonal tile only */                   \
            _Pragma("unroll") for (int mi = 0; mi < 2; ++mi)                         \
            _Pragma("unroll") for (int ni = 0; ni < 4; ++ni)                         \
            _Pragma("unroll") for (int r = 0; r < 4; ++r)                            \
                if ((kb) * 64 + ni * 16 + lr > spos + mi * 16 + kg * 4 + r)          \
                    sa[mi][ni][r] = -1e30f;                                          \
        }                                                                            \
        _Pragma("unroll") for (int mi = 0; mi < 2; ++mi)                             \
        _Pragma("unroll") for (int r = 0; r < 4; ++r) {                              \
            float mx = fmaxf(fmaxf(sa[mi][0][r], sa[mi][1][r]),                      \
                             fmaxf(sa[mi][2][r], sa[mi][3][r]));                     \
            _Pragma("unroll") for (int off = 1; off < 16; off <<= 1)                 \
                mx = fmaxf(mx, __shfl_xor(mx, off));                                 \
            float mo = m_run[mi][r];                                                 \
            float mn = fmaxf(mo, mx);                                                \
            float sc = __expf(mo - mn);                                              \
            float rs = 0.f;                                                          \
            _Pragma("unroll") for (int ni = 0; ni < 4; ++ni) {                       \
                float pv = __expf(sa[mi][ni][r] - mn);                               \
                sa[mi][ni][r] = pv;                                                  \
                rs += pv;                                                            \
            }                                                                        \
            _Pragma("unroll") for (int off = 1; off < 16; off <<= 1)                 \
                rs += __shfl_xor(rs, off);                                           \
            l_run[mi][r] = l_run[mi][r] * sc + rs;                                   \
            m_run[mi][r] = mn;                                                       \
            _Pragma("unroll") for (int ni = 0; ni < 4; ++ni) Oa[mi][ni][r] *= sc;    \
        }                                                                            \
        _Pragma("unroll") for (int mi = 0; mi < 2; ++mi)                             \
        _Pragma("unroll") for (int r = 0; r < 4; ++r)                                \
        _Pragma("unroll") for (int ni = 0; ni < 4; ++ni)                             \
            *(bf16_t*)(Pw + swz(mi * 16 + kg * 4 + r, (ni * 16 + lr) * 2)) =         \
                (bf16_t)sa[mi][ni][r];                                               \
        _Pragma("unroll") for (int s2 = 0; s2 < 2; ++s2) {                           \
            bf16x8 pf0 = *(const bf16x8*)(Pw + swz(lr, s2 * 64 + kg * 16));          \
            bf16x8 pf1 = *(const bf16x8*)(Pw + swz(16 + lr, s2 * 64 + kg * 16));     \
            _Pragma("unroll") for (int ni = 0; ni < 4; ++ni) {                       \
                Oa[0][ni] = __builtin_amdgcn_mfma_f32_16x16x32_bf16(                 \
                    pf0, vf[ni * 2 + s2], Oa[0][ni], 0, 0, 0);                       \
                Oa[1][ni] = __builtin_amdgcn_mfma_f32_16x16x32_bf16(                 \
                    pf1, vf[ni * 2 + s2], Oa[1][ni], 0, 0, 0);                       \
            }                                                                        \
        }                                                                            \
        if ((kb) < kbmax) { LOADV((kb) + 1, vfN); }                                  \
    }

#pragma unroll 1
    for (int half = 0; half < 2; ++half) {
        int s = half ? (63 - j) : j;   // strip id within (h,b)
        int spos = s * 32;             // sequence position of strip row 0
        int kbmax = s >> 1;

        bf16x8 qf[2][2];
#pragma unroll
        for (int mi = 0; mi < 2; ++mi)
#pragma unroll
            for (int s2 = 0; s2 < 2; ++s2)
                qf[mi][s2] = *(const bf16x8*)&Q[(size_t)(rowbase + spos + mi * 16 + lr) * DM +
                                                colbase + s2 * 32 + kg * 8];

        f32x4 Oa[2][4];
        float m_run[2][4], l_run[2][4];
#pragma unroll
        for (int mi = 0; mi < 2; ++mi)
#pragma unroll
            for (int ni = 0; ni < 4; ++ni) Oa[mi][ni] = (f32x4){0.f, 0.f, 0.f, 0.f};
#pragma unroll
        for (int mi = 0; mi < 2; ++mi)
#pragma unroll
            for (int r = 0; r < 4; ++r) { m_run[mi][r] = -1e30f; l_run[mi][r] = 0.f; }

        bf16x8 kfA[8], kfB[8], vfA[8], vfB[8];
        LOADK(0, kfA);
        LOADV(0, vfA);
#pragma unroll 1
        for (int kb = 0; kb <= kbmax; kb += 2) {
            STEP(kb, kfA, vfA, kfB, vfB);
            if (kb + 1 <= kbmax) STEP(kb + 1, kfB, vfB, kfA, vfA);
        }

#pragma unroll
        for (int mi = 0; mi < 2; ++mi)
#pragma unroll
            for (int r = 0; r < 4; ++r) {
                float inv = 1.f / l_run[mi][r];
                size_t row = (size_t)(rowbase + spos + mi * 16 + kg * 4 + r);
#pragma unroll
                for (int ni = 0; ni < 4; ++ni)
                    Ob[row * DM + colbase + ni * 16 + lr] = (bf16_t)(Oa[mi][ni][r] * inv);
            }
    }
#undef LOADK
#undef LOADV
#undef STEP
}

extern "C" void kernel_launch(void* const* d_in, const int* in_sizes, int n_in,
                              void* d_out, int out_size, void* d_ws, size_t ws_size,
                              hipStream_t stream) {
    const float* x  = (const float*)d_in[0];
    const float* wk = (const float*)d_in[1];  // key_weight
    const float* wq = (const float*)d_in[2];  // query_weight
    const float* wv = (const float*)d_in[3];  // value_weight
    const float* wo = (const float*)d_in[4];  // output_weight
    const float* sn = (const float*)d_in[5];
    const float* cs = (const float*)d_in[6];
    float* out = (float*)d_out;
    (void)in_sizes; (void)n_in; (void)out_size; (void)ws_size;

    char* ws = (char*)d_ws;
    const size_t MB = 1024 * 1024;
    bf16_t* xb  = (bf16_t*)(ws + 0);        // 4096x1024
    bf16_t* wqb = (bf16_t*)(ws + 8 * MB);   // 1024x1024
    bf16_t* wkb = (bf16_t*)(ws + 10 * MB);
    bf16_t* wvb = (bf16_t*)(ws + 12 * MB);
    bf16_t* wob = (bf16_t*)(ws + 14 * MB);
    bf16_t* Qb  = (bf16_t*)(ws + 16 * MB);  // 4096x1024
    bf16_t* Kb  = (bf16_t*)(ws + 24 * MB);  // 4096x1024
    bf16_t* Vtb = (bf16_t*)(ws + 32 * MB);  // 1024x4096 (V^T: [h*64+d][b*2048+s])
    bf16_t* Ob  = (bf16_t*)(ws + 40 * MB);  // 4096x1024

    k_cvt5<<<dim3(2048, 5), 256, 0, stream>>>(x, xb, wq, wqb, wk, wkb, wv, wvb, wo, wob);

    // Q/K projections: C[bp][h*64+d] = sum_m x[bp][m] * W[h*64+d][m]
    k_gemm_bt<bf16_t><<<dim3(8, 32, 2), 256, 0, stream>>>(
        xb, wqb, wkb, Qb, Kb, 4096, 1024, 1024);
    // V projection, output-transposed: Vt[h*64+d][b*2048+s] = sum_m Wv[hd][m] x[bs][m]
    k_gemm_bt<bf16_t><<<dim3(32, 8, 1), 256, 0, stream>>>(
        wvb, xb, xb, Vtb, Vtb, 1024, 4096, 1024);

    k_rope<<<dim3(8192, 2), 256, 0, stream>>>(Qb, Kb, sn, cs);

    k_flash<<<dim3(8, 16, 2), 256, 0, stream>>>(Qb, Kb, Vtb, Ob);

    // out[bp][m] = sum_hd Ob[bp][hd] * wo[m][hd]
    k_gemm_bt<float><<<dim3(8, 32, 1), 256, 0, stream>>>(
        Ob, wob, wob, out, out, 4096, 1024, 1024);
}

// Round 6
// 178.993 us; speedup vs baseline: 1.6193x; 1.0732x over previous
//
#include <hip/hip_runtime.h>
#include <hip/hip_bf16.h>
#include <stdint.h>

typedef __bf16 bf16_t;
typedef bf16_t bf16x4 __attribute__((ext_vector_type(4)));
typedef bf16_t bf16x8 __attribute__((ext_vector_type(8)));
typedef float  f32x4  __attribute__((ext_vector_type(4)));

#define GAS __attribute__((address_space(1)))
#define LAS __attribute__((address_space(3)))

__device__ inline void gld_lds16(const void* g, void* l) {
    __builtin_amdgcn_global_load_lds((const GAS void*)g, (LAS void*)l, 16, 0, 0);
}

// byte offset into a [rows][64] bf16 tile (128B rows), XOR-swizzled (T2)
__device__ inline int swz(int row, int colbyte) {
    return row * 128 + (colbyte ^ ((row & 7) << 4));
}

// ---------------- fp32 -> bf16 convert, all 5 tensors in one launch ----------------
__global__ __launch_bounds__(256) void k_cvt5(const float* __restrict__ i0, bf16_t* __restrict__ o0,
                                              const float* __restrict__ i1, bf16_t* __restrict__ o1,
                                              const float* __restrict__ i2, bf16_t* __restrict__ o2,
                                              const float* __restrict__ i3, bf16_t* __restrict__ o3,
                                              const float* __restrict__ i4, bf16_t* __restrict__ o4) {
    const float* in; bf16_t* out; int n;
    switch (blockIdx.y) {
        case 0: in = i0; out = o0; n = 4194304; break;
        case 1: in = i1; out = o1; n = 1048576; break;
        case 2: in = i2; out = o2; n = 1048576; break;
        case 3: in = i3; out = o3; n = 1048576; break;
        default: in = i4; out = o4; n = 1048576; break;
    }
    int i = (blockIdx.x * 256 + threadIdx.x) * 8;
    if (i >= n) return;
    f32x4 v0 = *(const f32x4*)(in + i);
    f32x4 v1 = *(const f32x4*)(in + i + 4);
    bf16x8 o;
    o[0] = (bf16_t)v0[0]; o[1] = (bf16_t)v0[1]; o[2] = (bf16_t)v0[2]; o[3] = (bf16_t)v0[3];
    o[4] = (bf16_t)v1[0]; o[5] = (bf16_t)v1[1]; o[6] = (bf16_t)v1[2]; o[7] = (bf16_t)v1[3];
    *(bf16x8*)(out + i) = o;
}

// ---------------- RoPE on bf16 [4096][1024], pairs along head-dim ----------------
__global__ __launch_bounds__(256) void k_rope(bf16_t* __restrict__ Q, bf16_t* __restrict__ Kt,
                                              const float* __restrict__ sn,
                                              const float* __restrict__ cs) {
    int idx = blockIdx.x * 256 + threadIdx.x;   // pair index, total 4096*512
    bf16_t* T = blockIdx.y ? Kt : Q;
    int row = idx >> 9;          // 0..4095
    int pi  = idx & 511;
    int h = pi >> 5, i = pi & 31;
    int p = row & 2047;
    float c = cs[p * 32 + i], s = sn[p * 32 + i];
    bf16_t* ptr = T + (size_t)row * 1024 + h * 64 + 2 * i;
    float e = (float)ptr[0], o = (float)ptr[1];
    ptr[0] = (bf16_t)(e * c - o * s);
    ptr[1] = (bf16_t)(e * s + o * c);
}

// ---------------- GEMM  C[M][N] = A[M][K] * B[N][K]^T  (bf16 in, OutT out) ----------------
template <typename OutT>
__global__ __launch_bounds__(256) void k_gemm_bt(
    const bf16_t* __restrict__ A,
    const bf16_t* __restrict__ B0, const bf16_t* __restrict__ B1,
    OutT* __restrict__ C0, OutT* __restrict__ C1,
    int M, int N, int K) {
    const bf16_t* B = blockIdx.z == 0 ? B0 : B1;
    OutT*         C = blockIdx.z == 0 ? C0 : C1;
    const int BK = 32;
    __shared__ bf16_t As[128 * BK];
    __shared__ bf16_t Bs[128 * BK];
    int tid = threadIdx.x;
    int lane = tid & 63, wid = tid >> 6;
    int row0 = blockIdx.y * 128, col0 = blockIdx.x * 128;
    int wr = (wid >> 1) * 64, wc = (wid & 1) * 64;
    int lr = lane & 15, kg = lane >> 4;

    f32x4 acc[4][4];
#pragma unroll
    for (int i = 0; i < 4; ++i)
#pragma unroll
        for (int j = 0; j < 4; ++j) acc[i][j] = (f32x4){0.f, 0.f, 0.f, 0.f};

    int ob = tid * 16;  // byte offset within a 4096-byte staging pass
    for (int k0 = 0; k0 < K; k0 += BK) {
        __syncthreads();
#pragma unroll
        for (int p = 0; p < 2; ++p) {
            int off = p * 4096 + ob;
            int r = off >> 6;      // 64 bytes per 32-elem row
            int cb = off & 63;
            gld_lds16((const char*)A + ((size_t)(row0 + r) * K + k0) * 2 + cb, (char*)As + off);
            gld_lds16((const char*)B + ((size_t)(col0 + r) * K + k0) * 2 + cb, (char*)Bs + off);
        }
        __syncthreads();
        bf16x8 af[4], bfr[4];
#pragma unroll
        for (int mi = 0; mi < 4; ++mi)
            af[mi] = *(const bf16x8*)&As[(wr + mi * 16 + lr) * BK + kg * 8];
#pragma unroll
        for (int ni = 0; ni < 4; ++ni)
            bfr[ni] = *(const bf16x8*)&Bs[(wc + ni * 16 + lr) * BK + kg * 8];
#pragma unroll
        for (int mi = 0; mi < 4; ++mi)
#pragma unroll
            for (int ni = 0; ni < 4; ++ni)
                acc[mi][ni] = __builtin_amdgcn_mfma_f32_16x16x32_bf16(af[mi], bfr[ni],
                                                                      acc[mi][ni], 0, 0, 0);
    }
#pragma unroll
    for (int mi = 0; mi < 4; ++mi)
#pragma unroll
        for (int ni = 0; ni < 4; ++ni)
#pragma unroll
            for (int r = 0; r < 4; ++r) {
                int row = row0 + wr + mi * 16 + kg * 4 + r;
                int col = col0 + wc + ni * 16 + lr;
                C[(size_t)row * N + col] = (OutT)acc[mi][ni][r];
            }
}

// ---------------- Flash attention, causal, wave-independent, swapped-QK^T ----------------
// grid (16, 16, 2) x 256 threads; one 32-q-row strip per wave (strip = wid*16+bx).
// S^T = mfma(K,Q): each lane owns ONE q per mi-block (q = lane&15) with 16 k-values
// in registers -> row softmax = in-reg reduce + 2 shuffles (xor16/xor32).
// K,V^T fragments read directly from global (L2-hot), prefetched 1 step ahead.
// P routed [q][k] through private swizzled LDS (b64 packed writes, b128 reads).
__global__ __launch_bounds__(256, 2) void k_flash(const bf16_t* __restrict__ Q,
                                                  const bf16_t* __restrict__ K,
                                                  const bf16_t* __restrict__ Vt,
                                                  bf16_t* __restrict__ Ob) {
    const int DM = 1024, S = 2048, NB = 4096;
    int h = blockIdx.y, b = blockIdx.z;
    int tid = threadIdx.x, lane = tid & 63, wid = tid >> 6;
    int lr = lane & 15, kg = lane >> 4;
    int rowbase = b * S;
    int colbase = h * 64;
    int s = wid * 16 + blockIdx.x;   // strip 0..63 within (h,b)
    int spos = s * 32;
    int kbmax = s >> 1;

    __shared__ bf16_t Ps[4][32 * 64];
    char* Pw = (char*)&Ps[wid][0];

    const bf16_t* Kg = K + (size_t)rowbase * DM + colbase;   // [k][d]
    const bf16_t* Vg = Vt + (size_t)colbase * NB + rowbase;  // [d][k]

#define LOADK(kb, dst)                                                               \
    _Pragma("unroll") for (int ni = 0; ni < 4; ++ni)                                 \
    _Pragma("unroll") for (int s2 = 0; s2 < 2; ++s2)                                 \
        dst[ni * 2 + s2] =                                                           \
            *(const bf16x8*)&Kg[(size_t)((kb) * 64 + ni * 16 + lr) * DM + s2 * 32 + kg * 8];

#define LOADV(kb, dst)                                                               \
    _Pragma("unroll") for (int nd = 0; nd < 4; ++nd)                                 \
    _Pragma("unroll") for (int s2 = 0; s2 < 2; ++s2)                                 \
        dst[nd * 2 + s2] =                                                           \
            *(const bf16x8*)&Vg[(size_t)(nd * 16 + lr) * NB + (kb) * 64 + s2 * 32 + kg * 8];

    // Q fragments (B-operand role: B[d][q], loaded once per strip)
    bf16x8 qf[2][2];
#pragma unroll
    for (int mi = 0; mi < 2; ++mi)
#pragma unroll
        for (int s2 = 0; s2 < 2; ++s2)
            qf[mi][s2] = *(const bf16x8*)&Q[(size_t)(rowbase + spos + mi * 16 + lr) * DM +
                                            colbase + s2 * 32 + kg * 8];

    f32x4 Oa[2][4];   // O^T[d = nd*16+kg*4+r][q = mi*16+lr]
    float m_run[2], l_run[2];
#pragma unroll
    for (int mi = 0; mi < 2; ++mi) {
        m_run[mi] = -1e30f;
        l_run[mi] = 0.f;
#pragma unroll
        for (int nd = 0; nd < 4; ++nd) Oa[mi][nd] = (f32x4){0.f, 0.f, 0.f, 0.f};
    }

    bf16x8 kf[8], vf[8];
    LOADK(0, kf);
    LOADV(0, vf);

#pragma unroll 1
    for (int kb = 0; kb <= kbmax; ++kb) {
        // ---- S^T = K * Q^T : sa[mi][ni][r] = S[q=spos+mi*16+lr][k=kb*64+ni*16+kg*4+r]
        f32x4 sa[2][4];
#pragma unroll
        for (int mi = 0; mi < 2; ++mi)
#pragma unroll
            for (int ni = 0; ni < 4; ++ni) sa[mi][ni] = (f32x4){0.f, 0.f, 0.f, 0.f};
#pragma unroll
        for (int s2 = 0; s2 < 2; ++s2)
#pragma unroll
            for (int ni = 0; ni < 4; ++ni)
#pragma unroll
                for (int mi = 0; mi < 2; ++mi)
                    sa[mi][ni] = __builtin_amdgcn_mfma_f32_16x16x32_bf16(
                        kf[ni * 2 + s2], qf[mi][s2], sa[mi][ni], 0, 0, 0);

        bool pre = kb < kbmax;
        if (pre) { LOADK(kb + 1, kf); }   // K latency hides under softmax+PV

        if (kb == kbmax) {   // causal mask, diagonal tile only
#pragma unroll
            for (int mi = 0; mi < 2; ++mi) {
                int qpos = spos + mi * 16 + lr;
#pragma unroll
                for (int ni = 0; ni < 4; ++ni)
#pragma unroll
                    for (int r = 0; r < 4; ++r)
                        if (kb * 64 + ni * 16 + kg * 4 + r > qpos) sa[mi][ni][r] = -1e30f;
            }
        }

        // ---- online softmax: lane owns q = mi*16+lr; 16 k-values in-reg + 2 shuffles
#pragma unroll
        for (int mi = 0; mi < 2; ++mi) {
            float mx = -1e30f;
#pragma unroll
            for (int ni = 0; ni < 4; ++ni)
                mx = fmaxf(mx, fmaxf(fmaxf(sa[mi][ni][0], sa[mi][ni][1]),
                                     fmaxf(sa[mi][ni][2], sa[mi][ni][3])));
            mx = fmaxf(mx, __shfl_xor(mx, 16));
            mx = fmaxf(mx, __shfl_xor(mx, 32));
            float mo = m_run[mi];
            float mn = fmaxf(mo, mx);
            float sc = __expf(mo - mn);
            m_run[mi] = mn;
            float rs = 0.f;
#pragma unroll
            for (int ni = 0; ni < 4; ++ni) {
                bf16x4 pk;
#pragma unroll
                for (int r = 0; r < 4; ++r) {
                    float pv = __expf(sa[mi][ni][r] - mn);
                    rs += pv;
                    pk[r] = (bf16_t)pv;
                }
                // P[q][k] : row = mi*16+lr, cols ni*16+kg*4 .. +3  (8B store, swizzled)
                *(bf16x4*)(Pw + swz(mi * 16 + lr, (ni * 16 + kg * 4) * 2)) = pk;
            }
            rs += __shfl_xor(rs, 16);
            rs += __shfl_xor(rs, 32);
            l_run[mi] = l_run[mi] * sc + rs;
#pragma unroll
            for (int nd = 0; nd < 4; ++nd) {
                Oa[mi][nd][0] *= sc; Oa[mi][nd][1] *= sc;
                Oa[mi][nd][2] *= sc; Oa[mi][nd][3] *= sc;
            }
        }

        // ---- O^T += V^T * P^T : A = vf (rows d), B = P^T read b128 from P[q][k] rows
#pragma unroll
        for (int mi = 0; mi < 2; ++mi) {
#pragma unroll
            for (int s2 = 0; s2 < 2; ++s2) {
                bf16x8 pf = *(const bf16x8*)(Pw + swz(mi * 16 + lr, s2 * 64 + kg * 16));
#pragma unroll
                for (int nd = 0; nd < 4; ++nd)
                    Oa[mi][nd] = __builtin_amdgcn_mfma_f32_16x16x32_bf16(
                        vf[nd * 2 + s2], pf, Oa[mi][nd], 0, 0, 0);
            }
        }

        if (pre) { LOADV(kb + 1, vf); }   // V latency hides across step boundary
    }

    // ---- epilogue: O[q][d] = O^T[d][q] / l ; lane writes 4 consecutive d per (mi,nd)
#pragma unroll
    for (int mi = 0; mi < 2; ++mi) {
        float inv = 1.f / l_run[mi];
        size_t row = (size_t)(rowbase + spos + mi * 16 + lr);
#pragma unroll
        for (int nd = 0; nd < 4; ++nd) {
            bf16x4 o;
#pragma unroll
            for (int r = 0; r < 4; ++r) o[r] = (bf16_t)(Oa[mi][nd][r] * inv);
            *(bf16x4*)&Ob[row * DM + colbase + nd * 16 + kg * 4] = o;
        }
    }
#undef LOADK
#undef LOADV
}

extern "C" void kernel_launch(void* const* d_in, const int* in_sizes, int n_in,
                              void* d_out, int out_size, void* d_ws, size_t ws_size,
                              hipStream_t stream) {
    const float* x  = (const float*)d_in[0];
    const float* wk = (const float*)d_in[1];  // key_weight
    const float* wq = (const float*)d_in[2];  // query_weight
    const float* wv = (const float*)d_in[3];  // value_weight
    const float* wo = (const float*)d_in[4];  // output_weight
    const float* sn = (const float*)d_in[5];
    const float* cs = (const float*)d_in[6];
    float* out = (float*)d_out;
    (void)in_sizes; (void)n_in; (void)out_size; (void)ws_size;

    char* ws = (char*)d_ws;
    const size_t MB = 1024 * 1024;
    bf16_t* xb  = (bf16_t*)(ws + 0);        // 4096x1024
    bf16_t* wqb = (bf16_t*)(ws + 8 * MB);   // 1024x1024
    bf16_t* wkb = (bf16_t*)(ws + 10 * MB);
    bf16_t* wvb = (bf16_t*)(ws + 12 * MB);
    bf16_t* wob = (bf16_t*)(ws + 14 * MB);
    bf16_t* Qb  = (bf16_t*)(ws + 16 * MB);  // 4096x1024
    bf16_t* Kb  = (bf16_t*)(ws + 24 * MB);  // 4096x1024
    bf16_t* Vtb = (bf16_t*)(ws + 32 * MB);  // 1024x4096 (V^T: [h*64+d][b*2048+s])
    bf16_t* Ob  = (bf16_t*)(ws + 40 * MB);  // 4096x1024

    k_cvt5<<<dim3(2048, 5), 256, 0, stream>>>(x, xb, wq, wqb, wk, wkb, wv, wvb, wo, wob);

    // Q/K projections: C[bp][h*64+d] = sum_m x[bp][m] * W[h*64+d][m]
    k_gemm_bt<bf16_t><<<dim3(8, 32, 2), 256, 0, stream>>>(
        xb, wqb, wkb, Qb, Kb, 4096, 1024, 1024);
    // V projection, output-transposed: Vt[h*64+d][b*2048+s] = sum_m Wv[hd][m] x[bs][m]
    k_gemm_bt<bf16_t><<<dim3(32, 8, 1), 256, 0, stream>>>(
        wvb, xb, xb, Vtb, Vtb, 1024, 4096, 1024);

    k_rope<<<dim3(8192, 2), 256, 0, stream>>>(Qb, Kb, sn, cs);

    k_flash<<<dim3(16, 16, 2), 256, 0, stream>>>(Qb, Kb, Vtb, Ob);

    // out[bp][m] = sum_hd Ob[bp][hd] * wo[m][hd]
    k_gemm_bt<float><<<dim3(8, 32, 1), 256, 0, stream>>>(
        Ob, wob, wob, out, out, 4096, 1024, 1024);
}

// Round 7
// 165.631 us; speedup vs baseline: 1.7499x; 1.0807x over previous
//
#include <hip/hip_runtime.h>
#include <hip/hip_bf16.h>
#include <stdint.h>

typedef __bf16 bf16_t;
typedef bf16_t bf16x4 __attribute__((ext_vector_type(4)));
typedef bf16_t bf16x8 __attribute__((ext_vector_type(8)));
typedef float  f32x4  __attribute__((ext_vector_type(4)));

#define GAS __attribute__((address_space(1)))
#define LAS __attribute__((address_space(3)))

__device__ inline void gld_lds16(const void* g, void* l) {
    __builtin_amdgcn_global_load_lds((const GAS void*)g, (LAS void*)l, 16, 0, 0);
}

// byte offset into a [rows][64] bf16 tile (128B rows), XOR-swizzled (T2)
__device__ inline int swz(int row, int colbyte) {
    return row * 128 + (colbyte ^ ((row & 7) << 4));
}

// ---------------- fp32 -> bf16 convert, all 5 tensors in one launch ----------------
__global__ __launch_bounds__(256) void k_cvt5(const float* __restrict__ i0, bf16_t* __restrict__ o0,
                                              const float* __restrict__ i1, bf16_t* __restrict__ o1,
                                              const float* __restrict__ i2, bf16_t* __restrict__ o2,
                                              const float* __restrict__ i3, bf16_t* __restrict__ o3,
                                              const float* __restrict__ i4, bf16_t* __restrict__ o4) {
    const float* in; bf16_t* out; int n;
    switch (blockIdx.y) {
        case 0: in = i0; out = o0; n = 4194304; break;
        case 1: in = i1; out = o1; n = 1048576; break;
        case 2: in = i2; out = o2; n = 1048576; break;
        case 3: in = i3; out = o3; n = 1048576; break;
        default: in = i4; out = o4; n = 1048576; break;
    }
    int i = (blockIdx.x * 256 + threadIdx.x) * 8;
    if (i >= n) return;
    f32x4 v0 = *(const f32x4*)(in + i);
    f32x4 v1 = *(const f32x4*)(in + i + 4);
    bf16x8 o;
    o[0] = (bf16_t)v0[0]; o[1] = (bf16_t)v0[1]; o[2] = (bf16_t)v0[2]; o[3] = (bf16_t)v0[3];
    o[4] = (bf16_t)v1[0]; o[5] = (bf16_t)v1[1]; o[6] = (bf16_t)v1[2]; o[7] = (bf16_t)v1[3];
    *(bf16x8*)(out + i) = o;
}

// ---------------- RoPE on bf16 [4096][1024], pairs along head-dim ----------------
__global__ __launch_bounds__(256) void k_rope(bf16_t* __restrict__ Q, bf16_t* __restrict__ Kt,
                                              const float* __restrict__ sn,
                                              const float* __restrict__ cs) {
    int idx = blockIdx.x * 256 + threadIdx.x;   // pair index, total 4096*512
    bf16_t* T = blockIdx.y ? Kt : Q;
    int row = idx >> 9;          // 0..4095
    int pi  = idx & 511;
    int h = pi >> 5, i = pi & 31;
    int p = row & 2047;
    float c = cs[p * 32 + i], s = sn[p * 32 + i];
    bf16_t* ptr = T + (size_t)row * 1024 + h * 64 + 2 * i;
    float e = (float)ptr[0], o = (float)ptr[1];
    ptr[0] = (bf16_t)(e * c - o * s);
    ptr[1] = (bf16_t)(e * s + o * c);
}

// ---------------- GEMM  C[M][N] = A[M][K] * B[N][K]^T  (bf16 in, OutT out) ----------------
template <typename OutT>
__global__ __launch_bounds__(256) void k_gemm_bt(
    const bf16_t* __restrict__ A,
    const bf16_t* __restrict__ B0, const bf16_t* __restrict__ B1,
    OutT* __restrict__ C0, OutT* __restrict__ C1,
    int M, int N, int K) {
    const bf16_t* B = blockIdx.z == 0 ? B0 : B1;
    OutT*         C = blockIdx.z == 0 ? C0 : C1;
    const int BK = 32;
    __shared__ bf16_t As[128 * BK];
    __shared__ bf16_t Bs[128 * BK];
    int tid = threadIdx.x;
    int lane = tid & 63, wid = tid >> 6;
    int row0 = blockIdx.y * 128, col0 = blockIdx.x * 128;
    int wr = (wid >> 1) * 64, wc = (wid & 1) * 64;
    int lr = lane & 15, kg = lane >> 4;

    f32x4 acc[4][4];
#pragma unroll
    for (int i = 0; i < 4; ++i)
#pragma unroll
        for (int j = 0; j < 4; ++j) acc[i][j] = (f32x4){0.f, 0.f, 0.f, 0.f};

    int ob = tid * 16;  // byte offset within a 4096-byte staging pass
    for (int k0 = 0; k0 < K; k0 += BK) {
        __syncthreads();
#pragma unroll
        for (int p = 0; p < 2; ++p) {
            int off = p * 4096 + ob;
            int r = off >> 6;      // 64 bytes per 32-elem row
            int cb = off & 63;
            gld_lds16((const char*)A + ((size_t)(row0 + r) * K + k0) * 2 + cb, (char*)As + off);
            gld_lds16((const char*)B + ((size_t)(col0 + r) * K + k0) * 2 + cb, (char*)Bs + off);
        }
        __syncthreads();
        bf16x8 af[4], bfr[4];
#pragma unroll
        for (int mi = 0; mi < 4; ++mi)
            af[mi] = *(const bf16x8*)&As[(wr + mi * 16 + lr) * BK + kg * 8];
#pragma unroll
        for (int ni = 0; ni < 4; ++ni)
            bfr[ni] = *(const bf16x8*)&Bs[(wc + ni * 16 + lr) * BK + kg * 8];
#pragma unroll
        for (int mi = 0; mi < 4; ++mi)
#pragma unroll
            for (int ni = 0; ni < 4; ++ni)
                acc[mi][ni] = __builtin_amdgcn_mfma_f32_16x16x32_bf16(af[mi], bfr[ni],
                                                                      acc[mi][ni], 0, 0, 0);
    }
#pragma unroll
    for (int mi = 0; mi < 4; ++mi)
#pragma unroll
        for (int ni = 0; ni < 4; ++ni)
#pragma unroll
            for (int r = 0; r < 4; ++r) {
                int row = row0 + wr + mi * 16 + kg * 4 + r;
                int col = col0 + wc + ni * 16 + lr;
                C[(size_t)row * N + col] = (OutT)acc[mi][ni][r];
            }
}

// ---------------- Flash attention, causal, wave-independent, swapped-QK^T ----------------
// grid (16, 16, 2) x 256 threads; one 32-q-row strip per wave.
// Duration-uniform mapping: block bx owns strip quad q (q = bx, or 15-bx for b=1 so
// that co-resident blocks sum to ~const work); wave wid takes strip 4q+wid so all
// 4 waves of a block run within 1 iter of each other (no early drain).
__global__ __launch_bounds__(256, 2) void k_flash(const bf16_t* __restrict__ Q,
                                                  const bf16_t* __restrict__ K,
                                                  const bf16_t* __restrict__ Vt,
                                                  bf16_t* __restrict__ Ob) {
    const int DM = 1024, S = 2048, NB = 4096;
    int h = blockIdx.y, b = blockIdx.z;
    int tid = threadIdx.x, lane = tid & 63, wid = tid >> 6;
    int lr = lane & 15, kg = lane >> 4;
    int rowbase = b * S;
    int colbase = h * 64;
    int quad = b ? (15 - (int)blockIdx.x) : (int)blockIdx.x;
    int s = quad * 4 + wid;          // strip 0..63 within (h,b)
    int spos = s * 32;
    int kbmax = s >> 1;

    __shared__ bf16_t Ps[4][32 * 64];
    char* Pw = (char*)&Ps[wid][0];

    const bf16_t* Kg = K + (size_t)rowbase * DM + colbase;   // [k][d]
    const bf16_t* Vg = Vt + (size_t)colbase * NB + rowbase;  // [d][k]

#define LOADK(kb, dst)                                                               \
    _Pragma("unroll") for (int ni = 0; ni < 4; ++ni)                                 \
    _Pragma("unroll") for (int s2 = 0; s2 < 2; ++s2)                                 \
        dst[ni * 2 + s2] =                                                           \
            *(const bf16x8*)&Kg[(size_t)((kb) * 64 + ni * 16 + lr) * DM + s2 * 32 + kg * 8];

#define LOADV(kb, dst)                                                               \
    _Pragma("unroll") for (int nd = 0; nd < 4; ++nd)                                 \
    _Pragma("unroll") for (int s2 = 0; s2 < 2; ++s2)                                 \
        dst[nd * 2 + s2] =                                                           \
            *(const bf16x8*)&Vg[(size_t)(nd * 16 + lr) * NB + (kb) * 64 + s2 * 32 + kg * 8];

    // Q fragments (B-operand role: B[d][q], loaded once per strip)
    bf16x8 qf[2][2];
#pragma unroll
    for (int mi = 0; mi < 2; ++mi)
#pragma unroll
        for (int s2 = 0; s2 < 2; ++s2)
            qf[mi][s2] = *(const bf16x8*)&Q[(size_t)(rowbase + spos + mi * 16 + lr) * DM +
                                            colbase + s2 * 32 + kg * 8];

    f32x4 Oa[2][4];   // O^T[d = nd*16+kg*4+r][q = mi*16+lr]
    float m_run[2], l_run[2];
#pragma unroll
    for (int mi = 0; mi < 2; ++mi) {
        m_run[mi] = -1e30f;
        l_run[mi] = 0.f;
#pragma unroll
        for (int nd = 0; nd < 4; ++nd) Oa[mi][nd] = (f32x4){0.f, 0.f, 0.f, 0.f};
    }

    bf16x8 kf[8], vf[8];
    LOADK(0, kf);
    LOADV(0, vf);

#pragma unroll 1
    for (int kb = 0; kb <= kbmax; ++kb) {
        // ---- S^T = K * Q^T : sa[mi][ni][r] = S[q=spos+mi*16+lr][k=kb*64+ni*16+kg*4+r]
        f32x4 sa[2][4];
#pragma unroll
        for (int mi = 0; mi < 2; ++mi)
#pragma unroll
            for (int ni = 0; ni < 4; ++ni) sa[mi][ni] = (f32x4){0.f, 0.f, 0.f, 0.f};
        __builtin_amdgcn_s_setprio(1);
#pragma unroll
        for (int s2 = 0; s2 < 2; ++s2)
#pragma unroll
            for (int ni = 0; ni < 4; ++ni)
#pragma unroll
                for (int mi = 0; mi < 2; ++mi)
                    sa[mi][ni] = __builtin_amdgcn_mfma_f32_16x16x32_bf16(
                        kf[ni * 2 + s2], qf[mi][s2], sa[mi][ni], 0, 0, 0);
        __builtin_amdgcn_s_setprio(0);

        bool pre = kb < kbmax;
        if (pre) { LOADK(kb + 1, kf); }   // K latency hides under softmax+PV

        if (kb == kbmax) {   // causal mask, diagonal tile only
#pragma unroll
            for (int mi = 0; mi < 2; ++mi) {
                int qpos = spos + mi * 16 + lr;
#pragma unroll
                for (int ni = 0; ni < 4; ++ni)
#pragma unroll
                    for (int r = 0; r < 4; ++r)
                        if (kb * 64 + ni * 16 + kg * 4 + r > qpos) sa[mi][ni][r] = -1e30f;
            }
        }

        // ---- online softmax: lane owns q = mi*16+lr; 16 k-values in-reg + 2 shuffles
#pragma unroll
        for (int mi = 0; mi < 2; ++mi) {
            float mx = -1e30f;
#pragma unroll
            for (int ni = 0; ni < 4; ++ni)
                mx = fmaxf(mx, fmaxf(fmaxf(sa[mi][ni][0], sa[mi][ni][1]),
                                     fmaxf(sa[mi][ni][2], sa[mi][ni][3])));
            mx = fmaxf(mx, __shfl_xor(mx, 16));
            mx = fmaxf(mx, __shfl_xor(mx, 32));
            float mo = m_run[mi];
            float mn = fmaxf(mo, mx);
            float sc = __expf(mo - mn);
            m_run[mi] = mn;
            float rs = 0.f;
#pragma unroll
            for (int ni = 0; ni < 4; ++ni) {
                bf16x4 pk;
#pragma unroll
                for (int r = 0; r < 4; ++r) {
                    float pv = __expf(sa[mi][ni][r] - mn);
                    rs += pv;
                    pk[r] = (bf16_t)pv;
                }
                // P[q][k] : row = mi*16+lr, cols ni*16+kg*4 .. +3  (8B store, swizzled)
                *(bf16x4*)(Pw + swz(mi * 16 + lr, (ni * 16 + kg * 4) * 2)) = pk;
            }
            rs += __shfl_xor(rs, 16);
            rs += __shfl_xor(rs, 32);
            l_run[mi] = l_run[mi] * sc + rs;
#pragma unroll
            for (int nd = 0; nd < 4; ++nd) {
                Oa[mi][nd][0] *= sc; Oa[mi][nd][1] *= sc;
                Oa[mi][nd][2] *= sc; Oa[mi][nd][3] *= sc;
            }
        }

        // ---- O^T += V^T * P^T : A = vf (rows d), B = P^T read b128 from P[q][k] rows
#pragma unroll
        for (int mi = 0; mi < 2; ++mi) {
#pragma unroll
            for (int s2 = 0; s2 < 2; ++s2) {
                bf16x8 pf = *(const bf16x8*)(Pw + swz(mi * 16 + lr, s2 * 64 + kg * 16));
                __builtin_amdgcn_s_setprio(1);
#pragma unroll
                for (int nd = 0; nd < 4; ++nd)
                    Oa[mi][nd] = __builtin_amdgcn_mfma_f32_16x16x32_bf16(
                        vf[nd * 2 + s2], pf, Oa[mi][nd], 0, 0, 0);
                __builtin_amdgcn_s_setprio(0);
            }
        }

        if (pre) { LOADV(kb + 1, vf); }   // V latency hides across step boundary
    }

    // ---- epilogue: O[q][d] = O^T[d][q] / l ; lane writes 4 consecutive d per (mi,nd)
#pragma unroll
    for (int mi = 0; mi < 2; ++mi) {
        float inv = 1.f / l_run[mi];
        size_t row = (size_t)(rowbase + spos + mi * 16 + lr);
#pragma unroll
        for (int nd = 0; nd < 4; ++nd) {
            bf16x4 o;
#pragma unroll
            for (int r = 0; r < 4; ++r) o[r] = (bf16_t)(Oa[mi][nd][r] * inv);
            *(bf16x4*)&Ob[row * DM + colbase + nd * 16 + kg * 4] = o;
        }
    }
#undef LOADK
#undef LOADV
}

extern "C" void kernel_launch(void* const* d_in, const int* in_sizes, int n_in,
                              void* d_out, int out_size, void* d_ws, size_t ws_size,
                              hipStream_t stream) {
    const float* x  = (const float*)d_in[0];
    const float* wk = (const float*)d_in[1];  // key_weight
    const float* wq = (const float*)d_in[2];  // query_weight
    const float* wv = (const float*)d_in[3];  // value_weight
    const float* wo = (const float*)d_in[4];  // output_weight
    const float* sn = (const float*)d_in[5];
    const float* cs = (const float*)d_in[6];
    float* out = (float*)d_out;
    (void)in_sizes; (void)n_in; (void)out_size; (void)ws_size;

    char* ws = (char*)d_ws;
    const size_t MB = 1024 * 1024;
    bf16_t* xb  = (bf16_t*)(ws + 0);        // 4096x1024
    bf16_t* wqb = (bf16_t*)(ws + 8 * MB);   // 1024x1024
    bf16_t* wkb = (bf16_t*)(ws + 10 * MB);
    bf16_t* wvb = (bf16_t*)(ws + 12 * MB);
    bf16_t* wob = (bf16_t*)(ws + 14 * MB);
    bf16_t* Qb  = (bf16_t*)(ws + 16 * MB);  // 4096x1024
    bf16_t* Kb  = (bf16_t*)(ws + 24 * MB);  // 4096x1024
    bf16_t* Vtb = (bf16_t*)(ws + 32 * MB);  // 1024x4096 (V^T: [h*64+d][b*2048+s])
    bf16_t* Ob  = (bf16_t*)(ws + 40 * MB);  // 4096x1024

    k_cvt5<<<dim3(2048, 5), 256, 0, stream>>>(x, xb, wq, wqb, wk, wkb, wv, wvb, wo, wob);

    // Q/K projections: C[bp][h*64+d] = sum_m x[bp][m] * W[h*64+d][m]
    k_gemm_bt<bf16_t><<<dim3(8, 32, 2), 256, 0, stream>>>(
        xb, wqb, wkb, Qb, Kb, 4096, 1024, 1024);
    // V projection, output-transposed: Vt[h*64+d][b*2048+s] = sum_m Wv[hd][m] x[bs][m]
    k_gemm_bt<bf16_t><<<dim3(32, 8, 1), 256, 0, stream>>>(
        wvb, xb, xb, Vtb, Vtb, 1024, 4096, 1024);

    k_rope<<<dim3(8192, 2), 256, 0, stream>>>(Qb, Kb, sn, cs);

    k_flash<<<dim3(16, 16, 2), 256, 0, stream>>>(Qb, Kb, Vtb, Ob);

    // out[bp][m] = sum_hd Ob[bp][hd] * wo[m][hd]
    k_gemm_bt<float><<<dim3(8, 32, 1), 256, 0, stream>>>(
        Ob, wob, wob, out, out, 4096, 1024, 1024);
}